// Round 4
// baseline (187.581 us; speedup 1.0000x reference)
//
#include <hip/hip_runtime.h>
#include <hip/hip_bf16.h>
#include <cstdint>
#include <cstddef>

// GAU fused pipeline. Global buffers fp32 (per harness npz sizes); internal GEMMs bf16 MFMA.
// B=16 C=256 H=W=64 (HW=4096) S=128 O=256. Workspace: 66 MiB.

typedef __attribute__((ext_vector_type(8))) short short8;     // 8 bf16 = MFMA A/B frag
typedef __attribute__((ext_vector_type(4))) float f32x4;
typedef __attribute__((ext_vector_type(2))) float f32x2;
typedef __attribute__((ext_vector_type(4))) unsigned int uint4v;

#define DI __device__ __forceinline__

DI unsigned int f2bf(float f){ unsigned int i; __builtin_memcpy(&i,&f,4); return (i + 0x7fffu + ((i>>16)&1u))>>16; }
DI float bf2f(unsigned short u){ unsigned int i = ((unsigned int)u)<<16; float f; __builtin_memcpy(&f,&i,4); return f; }

DI void gload16(const void* g, void* l){
  __builtin_amdgcn_global_load_lds((const __attribute__((address_space(1))) void*)g,
                                   (__attribute__((address_space(3))) void*)l, 16, 0, 0);
}

// ---------------- K0: pack weights fp32->bf16 + biases ----------------
// Wcat layout: [nt(5)][ks(4)][k8(8)][n(128)][8]  (o=nt*128+n, c=ks*64+k8*8+j; nt 0-1 gate, 2-3 value, 4 z)
// proj layout: [mt(2)][ks(4)][k8(8)][m(128)][8]
__global__ __launch_bounds__(256) void k_pack_w(
    const float* __restrict__ gW, const float* __restrict__ vW,
    const float* __restrict__ zW, const float* __restrict__ pW,
    const float* __restrict__ gB, const float* __restrict__ vB,
    const float* __restrict__ zB, const float* __restrict__ pB,
    unsigned short* __restrict__ wcat, unsigned short* __restrict__ proj,
    float* __restrict__ biases){
  int id = blockIdx.x*256 + threadIdx.x;
  if (id < 20480){
    int n=id&127, k8=(id>>7)&7, ks=(id>>10)&3, nt=id>>12;
    int o = nt*128+n, c0 = ks*64+k8*8;
    const float* src = (o<256) ? gW + (size_t)o*256 + c0
                      : (o<512) ? vW + (size_t)(o-256)*256 + c0
                      :           zW + (size_t)(o-512)*256 + c0;
    f32x4 a = *(const f32x4*)src, b = *(const f32x4*)(src+4);
    uint4v ov;
    ov[0] = f2bf(a[0]) | (f2bf(a[1])<<16);
    ov[1] = f2bf(a[2]) | (f2bf(a[3])<<16);
    ov[2] = f2bf(b[0]) | (f2bf(b[1])<<16);
    ov[3] = f2bf(b[2]) | (f2bf(b[3])<<16);
    *(uint4v*)(wcat + (size_t)id*8) = ov;
  } else if (id < 28672){
    int q = id - 20480;
    int m=q&127, k8=(q>>7)&7, ks=(q>>10)&3, mt=q>>12;
    int o = mt*128+m, c0 = ks*64+k8*8;
    const float* src = pW + (size_t)o*256 + c0;
    f32x4 a = *(const f32x4*)src, b = *(const f32x4*)(src+4);
    uint4v ov;
    ov[0] = f2bf(a[0]) | (f2bf(a[1])<<16);
    ov[1] = f2bf(a[2]) | (f2bf(a[3])<<16);
    ov[2] = f2bf(b[0]) | (f2bf(b[1])<<16);
    ov[3] = f2bf(b[2]) | (f2bf(b[3])<<16);
    *(uint4v*)(proj + (size_t)q*8) = ov;
  }
  if (id < 640) biases[id] = id<256 ? gB[id] : id<512 ? vB[id-256] : zB[id-512];
  if (id < 256) biases[640+id] = pB[id];
}

// ---------------- K1: per-(b,c) mean / rstd over 4096 (fp32 x) ----------------
__global__ __launch_bounds__(256) void k_stats(const float* __restrict__ x, float* __restrict__ stats){
  int bc = blockIdx.x, t = threadIdx.x, lane = t&63, wid = t>>6;
  const f32x4* row = (const f32x4*)(x + (size_t)bc*4096);
  float s=0.f, q=0.f;
  #pragma unroll
  for (int i=0;i<4;i++){
    f32x4 v = row[i*256+t];
    #pragma unroll
    for (int w=0;w<4;w++){ s += v[w]; q += v[w]*v[w]; }
  }
  #pragma unroll
  for (int off=32; off; off>>=1){ s += __shfl_xor(s,off); q += __shfl_xor(q,off); }
  __shared__ float r1[4], r2[4];
  if (lane==0){ r1[wid]=s; r2[wid]=q; }
  __syncthreads();
  if (t==0){
    float S=r1[0]+r1[1]+r1[2]+r1[3], Q=r2[0]+r2[1]+r2[2]+r2[3];
    float mu = S*(1.0f/4096.0f);
    float var = Q*(1.0f/4096.0f) - mu*mu;
    stats[bc*2]   = mu;
    stats[bc*2+1] = rsqrtf(var + 1e-5f);
  }
}

// ---------------- K2: normalize + pack xn (bf16) ----------------
// apack: [b(16)][mt(32)][ks(4)][k8(8)][m(128)][8], elem = xn[b][c=ks*64+k8*8+j][hw=mt*128+m]
__global__ __launch_bounds__(256) void k_xn_pack(const float* __restrict__ x,
    const float* __restrict__ stats, unsigned short* __restrict__ apack){
  size_t id = (size_t)blockIdx.x*256 + threadIdx.x;
  int m=(int)(id&127), k8=(int)(id>>7)&7, ks=(int)(id>>10)&3, mt=(int)(id>>12)&31, b=(int)(id>>17);
  int hw = mt*128+m, c0 = ks*64+k8*8;
  const float* xp = x + ((size_t)(b*256 + c0))*4096 + hw;
  const float* st = stats + (size_t)(b*256+c0)*2;
  uint4v o;
  #pragma unroll
  for (int j=0;j<8;j+=2){
    float v0 = (xp[(size_t)j*4096]     - st[j*2])   * st[j*2+1];
    float v1 = (xp[(size_t)(j+1)*4096] - st[j*2+2]) * st[j*2+3];
    o[j>>1] = f2bf(v0) | (f2bf(v1)<<16);
  }
  *(uint4v*)(apack + id*8) = o;
}

// ---------------- GEMM: C[128x128] = A[128x256]*B[256x128] (+bias), fp32 out ----------------
// A,B bf16 packed [ks(4)][k8(8)][dim(128)][8]; tile stride 32768 elems.
// EPI: 0 = C=acc+bias[n]; 1 = C *= (acc+bias[n]); 3 = C=acc+bias[m]
template<int EPI>
__global__ __launch_bounds__(256,2) void k_gemm(
    const unsigned short* __restrict__ Ap, const unsigned short* __restrict__ Bp,
    float* __restrict__ C, const float* __restrict__ bias,
    int nMT, int nNT, int aTPB, int bTPB, int ldc, long long cBatch){
  __shared__ alignas(16) unsigned short lds[2][2][8192];   // [buf][A/B][128x64 bf16]
  int bid = blockIdx.x;
  int per = nMT*nNT;
  int b = bid/per; int r = bid - b*per; int mt = r/nNT; int nt = r - mt*nNT;
  const unsigned short* At = Ap + (size_t)(b*aTPB + mt)*32768;
  const unsigned short* Bt = Bp + (size_t)(b*bTPB + nt)*32768;
  int t = threadIdx.x, lane = t&63, wid = t>>6;
  int wr = wid>>1, wc = wid&1;
  f32x4 acc[4][4] = {};

  #define STAGE(buf, kss) do{ \
    const unsigned short* ga = At + (kss)*8192; \
    const unsigned short* gb = Bt + (kss)*8192; \
    _Pragma("unroll") \
    for (int i_=0;i_<4;i_++){ int off_=(i_*256+t)*8; \
      gload16(ga+off_, &lds[buf][0][off_]); \
      gload16(gb+off_, &lds[buf][1][off_]); } \
  }while(0)

  STAGE(0,0);
  __syncthreads();
  #pragma unroll
  for (int ks=0; ks<4; ++ks){
    int cur = ks&1;
    if (ks<3) STAGE(cur^1, ks+1);
    #pragma unroll
    for (int kf=0; kf<2; ++kf){
      int k8 = kf*4 + (lane>>4);
      short8 af[4], bfr[4];
      #pragma unroll
      for (int i=0;i<4;i++){
        af[i]  = *(const short8*)&lds[cur][0][(size_t)(k8*128 + wr*64 + i*16 + (lane&15))*8];
        bfr[i] = *(const short8*)&lds[cur][1][(size_t)(k8*128 + wc*64 + i*16 + (lane&15))*8];
      }
      #pragma unroll
      for (int i=0;i<4;i++)
        #pragma unroll
        for (int j=0;j<4;j++)
          acc[i][j] = __builtin_amdgcn_mfma_f32_16x16x32_bf16(af[i], bfr[j], acc[i][j], 0,0,0);
    }
    __syncthreads();
  }
  float* Cb = C + (size_t)b*cBatch;
  #pragma unroll
  for (int i=0;i<4;i++){
    int mbase = mt*128 + wr*64 + i*16 + ((lane>>4)<<2);
    #pragma unroll
    for (int j=0;j<4;j++){
      int n = nt*128 + wc*64 + j*16 + (lane&15);
      float bn = (EPI==3) ? 0.0f : bias[n];
      #pragma unroll
      for (int rr=0; rr<4; ++rr){
        int m = mbase + rr;
        float v = acc[i][j][rr] + (EPI==3 ? bias[m] : bn);
        size_t idx = (size_t)m*ldc + n;
        if (EPI==1) v *= Cb[idx];
        Cb[idx] = v;
      }
    }
  }
  #undef STAGE
}

// ---------------- K3: affine + 2D RoPE + q.k -> sim (all fp32) ----------------
// zbuf[b][hw][128]. One wave per position; lane = channel pair.
__global__ __launch_bounds__(256) void k_sim(const float* __restrict__ zbuf,
    const float* __restrict__ gamma, const float* __restrict__ beta,
    float* __restrict__ sim){
  int pos = blockIdx.x*4 + (threadIdx.x>>6);
  int lane = threadIdx.x & 63;
  int b = pos>>12, hw = pos&4095;
  int h = hw>>6, w = hw&63;
  f32x2 z2 = *(const f32x2*)(zbuf + ((size_t)b*4096+hw)*128 + 2*lane);
  f32x2 g0 = *(const f32x2*)(gamma + 2*lane);
  f32x2 g1 = *(const f32x2*)(gamma + 128 + 2*lane);
  f32x2 b0 = *(const f32x2*)(beta + 2*lane);
  f32x2 b1 = *(const f32x2*)(beta + 128 + 2*lane);
  float q0 = z2[0]*g0[0] + b0[0], q1 = z2[1]*g0[1] + b0[1];
  float k0 = z2[0]*g1[0] + b1[0], k1 = z2[1]*g1[1] + b1[1];
  float fidx = (float)(lane&31);
  float inv = expf(fidx * -0.28782313662425574f);  // ln(10000)/32
  float p = (lane<32) ? (float)h : (float)w;
  float ang = p*inv, sn, cs;
  sincosf(ang, &sn, &cs);
  float q0r = q0*cs - q1*sn, q1r = q0*sn + q1*cs;
  float k0r = k0*cs - k1*sn, k1r = k0*sn + k1*cs;
  float part = q0r*k0r + q1r*k1r;
  #pragma unroll
  for (int off=32; off; off>>=1) part += __shfl_xor(part, off);
  if (lane==0) sim[pos] = part * 0.08838834764831845f;  // 1/sqrt(128)
}

// ---------------- K4: per-batch softmax over 4096, A -> d_out A-region (fp32) ----------------
__global__ __launch_bounds__(256) void k_softmax(const float* __restrict__ sim, float* __restrict__ A){
  int b = blockIdx.x, t = threadIdx.x, lane = t&63, wid = t>>6;
  const f32x4* s4 = (const f32x4*)(sim + (size_t)b*4096);
  f32x4 v[4];
  float mx = -3.4e38f;
  #pragma unroll
  for (int i=0;i<4;i++){
    v[i] = s4[i*256+t];
    #pragma unroll
    for (int w=0;w<4;w++) mx = fmaxf(mx, v[i][w]);
  }
  #pragma unroll
  for (int off=32; off; off>>=1) mx = fmaxf(mx, __shfl_xor(mx, off));
  __shared__ float sr1[4], sr2[4];
  if (lane==0) sr1[wid]=mx;
  __syncthreads();
  mx = fmaxf(fmaxf(sr1[0],sr1[1]), fmaxf(sr1[2],sr1[3]));
  float sum=0.f;
  #pragma unroll
  for (int i=0;i<4;i++)
    #pragma unroll
    for (int w=0;w<4;w++){ float e = expf(v[i][w]-mx); v[i][w]=e; sum+=e; }
  #pragma unroll
  for (int off=32; off; off>>=1) sum += __shfl_xor(sum, off);
  if (lane==0) sr2[wid]=sum;
  __syncthreads();
  sum = sr2[0]+sr2[1]+sr2[2]+sr2[3];
  float invs = 1.0f/sum;
  f32x4* Ab = (f32x4*)(A + (size_t)b*4096);
  #pragma unroll
  for (int i=0;i<4;i++){
    f32x4 a;
    #pragma unroll
    for (int w=0;w<4;w++) a[w] = v[i][w]*invs;
    Ab[i*256+t] = a;
  }
}

// ---------------- K5: V = A*(g*v) + xn, bf16 in-place into apack ----------------
__global__ __launch_bounds__(256) void k_vcompute(unsigned short* __restrict__ apack,
    const float* __restrict__ gv, const float* __restrict__ A){
  size_t id = (size_t)blockIdx.x*256 + threadIdx.x;
  int m=(int)(id&127), k8=(int)(id>>7)&7, ks=(int)(id>>10)&3, mt=(int)(id>>12)&31, b=(int)(id>>17);
  int hw = mt*128+m, c0 = ks*64+k8*8;
  float a = A[(size_t)b*4096 + hw];
  const float* gp = gv + ((size_t)b*4096+hw)*256 + c0;
  f32x4 g0 = *(const f32x4*)gp, g1 = *(const f32x4*)(gp+4);
  uint4v xx = *(const uint4v*)(apack + id*8);
  uint4v o;
  float r[8];
  r[0]=a*g0[0]; r[1]=a*g0[1]; r[2]=a*g0[2]; r[3]=a*g0[3];
  r[4]=a*g1[0]; r[5]=a*g1[1]; r[6]=a*g1[2]; r[7]=a*g1[3];
  #pragma unroll
  for (int w=0; w<4; w++){
    float xA = bf2f((unsigned short)(xx[w]&0xffff)), xB = bf2f((unsigned short)(xx[w]>>16));
    o[w] = f2bf(r[2*w]+xA) | (f2bf(r[2*w+1]+xB)<<16);
  }
  *(uint4v*)(apack + id*8) = o;
}

// ---------------- launch ----------------
extern "C" void kernel_launch(void* const* d_in, const int* in_sizes, int n_in,
                              void* d_out, int out_size, void* d_ws, size_t ws_size,
                              hipStream_t stream){
  const float* x  = (const float*)d_in[0];
  const float* gW = (const float*)d_in[1];
  const float* gB = (const float*)d_in[2];
  const float* vW = (const float*)d_in[3];
  const float* vB = (const float*)d_in[4];
  const float* zW = (const float*)d_in[5];
  const float* zB = (const float*)d_in[6];
  const float* gm = (const float*)d_in[7];
  const float* bt = (const float*)d_in[8];
  const float* pW = (const float*)d_in[9];
  const float* pB = (const float*)d_in[10];

  char* ws = (char*)d_ws;
  float* stats          = (float*)(ws + 0);                  //  32 KB
  float* biases         = (float*)(ws + 32768);              //  3.5 KB
  float* sim            = (float*)(ws + 40960);              // 256 KB
  unsigned short* wcat  = (unsigned short*)(ws + 303104);    // 640 KB bf16
  unsigned short* proj  = (unsigned short*)(ws + 958464);    // 256 KB bf16
  unsigned short* apack = (unsigned short*)(ws + 2097152);   // 32 MiB bf16 (xn, later V in-place)
  float* zbuf           = (float*)(ws + 35651584);           // 32 MiB fp32 -> total 69,206,016 B (66 MiB)

  float* out = (float*)d_out;
  float* gv  = out;             // g (then g*v) staged in out-region; overwritten by proj GEMM
  float* A   = out + 16777216;  // A output after 16x256x64x64

  hipLaunchKernelGGL(k_pack_w,  dim3(112),  dim3(256), 0, stream, gW, vW, zW, pW, gB, vB, zB, pB, wcat, proj, biases);
  hipLaunchKernelGGL(k_stats,   dim3(4096), dim3(256), 0, stream, x, stats);
  hipLaunchKernelGGL(k_xn_pack, dim3(8192), dim3(256), 0, stream, x, stats, apack);
  // gate: gv = xn^T @ Wg^T + bg           (M=4096/batch, N=256, K=256)
  hipLaunchKernelGGL((k_gemm<0>), dim3(16*32*2), dim3(256), 0, stream,
                     apack, wcat,           gv,   biases,     32, 2, 32, 0, 256, (long long)4096*256);
  // value: gv *= xn^T @ Wv^T + bv
  hipLaunchKernelGGL((k_gemm<1>), dim3(16*32*2), dim3(256), 0, stream,
                     apack, wcat + 2*32768, gv,   biases+256, 32, 2, 32, 0, 256, (long long)4096*256);
  // z: zbuf = xn^T @ Wz^T + bz            (M=4096/batch, N=128, K=256)
  hipLaunchKernelGGL((k_gemm<0>), dim3(16*32*1), dim3(256), 0, stream,
                     apack, wcat + 4*32768, zbuf, biases+512, 32, 1, 32, 0, 128, (long long)4096*128);
  hipLaunchKernelGGL(k_sim,     dim3(16384), dim3(256), 0, stream, zbuf, gm, bt, sim);
  hipLaunchKernelGGL(k_softmax, dim3(16),    dim3(256), 0, stream, sim, A);
  hipLaunchKernelGGL(k_vcompute,dim3(8192),  dim3(256), 0, stream, apack, gv, A);
  // proj: out[b][o][hw] = proj_W @ V + proj_b   (M=256, N=4096/batch, K=256)
  hipLaunchKernelGGL((k_gemm<3>), dim3(16*2*32), dim3(256), 0, stream,
                     proj, apack, out, biases+640, 2, 32, 0, 32, 4096, (long long)256*4096);
  (void)in_sizes; (void)n_in; (void)out_size; (void)ws_size;
}

// Round 5
// 135.103 us; speedup vs baseline: 1.3884x; 1.3884x over previous
//
#include <hip/hip_runtime.h>
#include <hip/hip_bf16.h>
#include <cstdint>
#include <cstddef>

// GAU fused pipeline. fp32 I/O; bf16 MFMA internally.
// B=16 C=256 H=W=64 (HW=4096) S=128 O=256. ws: 34 MiB; gv/z staged in d_out.

typedef __attribute__((ext_vector_type(8))) short short8;     // 8 bf16 MFMA frag
typedef __attribute__((ext_vector_type(4))) float f32x4;
typedef __attribute__((ext_vector_type(2))) float f32x2;
typedef __attribute__((ext_vector_type(4))) unsigned int uint4v;
typedef __attribute__((ext_vector_type(2))) unsigned int uint2v;

#define DI __device__ __forceinline__

DI unsigned int f2bf(float f){ unsigned int i; __builtin_memcpy(&i,&f,4); return (i + 0x7fffu + ((i>>16)&1u))>>16; }
DI float bf2f(unsigned short u){ unsigned int i = ((unsigned int)u)<<16; float f; __builtin_memcpy(&f,&i,4); return f; }

DI void gload16(const void* g, void* l){
  __builtin_amdgcn_global_load_lds((const __attribute__((address_space(1))) void*)g,
                                   (__attribute__((address_space(3))) void*)l, 16, 0, 0);
}

// ---------------- K0: pack weights fp32->bf16 + biases ----------------
// wcat: [nt(5)][ks(4)][k8(8)][n(128)][8]  (o=nt*128+n, c=ks*64+k8*8+j; nt 0-1 gate, 2-3 value, 4 z)
// proj: [oh(2)][ks(4)][k8(8)][o(128)][8]
__global__ __launch_bounds__(256) void k_pack_w(
    const float* __restrict__ gW, const float* __restrict__ vW,
    const float* __restrict__ zW, const float* __restrict__ pW,
    const float* __restrict__ gB, const float* __restrict__ vB,
    const float* __restrict__ zB, const float* __restrict__ pB,
    unsigned short* __restrict__ wcat, unsigned short* __restrict__ proj,
    float* __restrict__ biases){
  int id = blockIdx.x*256 + threadIdx.x;
  if (id < 20480){
    int n=id&127, k8=(id>>7)&7, ks=(id>>10)&3, nt=id>>12;
    int o = nt*128+n, c0 = ks*64+k8*8;
    const float* src = (o<256) ? gW + (size_t)o*256 + c0
                      : (o<512) ? vW + (size_t)(o-256)*256 + c0
                      :           zW + (size_t)(o-512)*256 + c0;
    f32x4 a = *(const f32x4*)src, b = *(const f32x4*)(src+4);
    uint4v ov;
    ov[0] = f2bf(a[0]) | (f2bf(a[1])<<16);
    ov[1] = f2bf(a[2]) | (f2bf(a[3])<<16);
    ov[2] = f2bf(b[0]) | (f2bf(b[1])<<16);
    ov[3] = f2bf(b[2]) | (f2bf(b[3])<<16);
    *(uint4v*)(wcat + (size_t)id*8) = ov;
  } else if (id < 28672){
    int q = id - 20480;
    int m=q&127, k8=(q>>7)&7, ks=(q>>10)&3, mt=q>>12;
    int o = mt*128+m, c0 = ks*64+k8*8;
    const float* src = pW + (size_t)o*256 + c0;
    f32x4 a = *(const f32x4*)src, b = *(const f32x4*)(src+4);
    uint4v ov;
    ov[0] = f2bf(a[0]) | (f2bf(a[1])<<16);
    ov[1] = f2bf(a[2]) | (f2bf(a[3])<<16);
    ov[2] = f2bf(b[0]) | (f2bf(b[1])<<16);
    ov[3] = f2bf(b[2]) | (f2bf(b[3])<<16);
    *(uint4v*)(proj + (size_t)q*8) = ov;
  }
  if (id < 640) biases[id] = id<256 ? gB[id] : id<512 ? vB[id-256] : zB[id-512];
  if (id < 256) biases[640+id] = pB[id];
}

// ---------------- K1: per-(b,c) mean / rstd over 4096 ----------------
__global__ __launch_bounds__(256) void k_stats(const float* __restrict__ x, float* __restrict__ stats){
  int bc = blockIdx.x, t = threadIdx.x, lane = t&63, wid = t>>6;
  const f32x4* row = (const f32x4*)(x + (size_t)bc*4096);
  float s=0.f, q=0.f;
  #pragma unroll
  for (int i=0;i<4;i++){
    f32x4 v = row[i*256+t];
    #pragma unroll
    for (int w=0;w<4;w++){ s += v[w]; q += v[w]*v[w]; }
  }
  #pragma unroll
  for (int off=32; off; off>>=1){ s += __shfl_xor(s,off); q += __shfl_xor(q,off); }
  __shared__ float r1[4], r2[4];
  if (lane==0){ r1[wid]=s; r2[wid]=q; }
  __syncthreads();
  if (t==0){
    float S=r1[0]+r1[1]+r1[2]+r1[3], Q=r2[0]+r2[1]+r2[2]+r2[3];
    float mu = S*(1.0f/4096.0f);
    float var = Q*(1.0f/4096.0f) - mu*mu;
    stats[bc*2]   = mu;
    stats[bc*2+1] = rsqrtf(var + 1e-5f);
  }
}

// ---------------- K2: normalize + pack xn (bf16) ----------------
// apack: [b(16)][mt(32)][ks(4)][k8(8)][m(128)][8], elem = xn[b][c=ks*64+k8*8+j][hw=mt*128+m]
__global__ __launch_bounds__(256) void k_xn_pack(const float* __restrict__ x,
    const float* __restrict__ stats, unsigned short* __restrict__ apack){
  size_t id = (size_t)blockIdx.x*256 + threadIdx.x;
  int m=(int)(id&127), k8=(int)(id>>7)&7, ks=(int)(id>>10)&3, mt=(int)(id>>12)&31, b=(int)(id>>17);
  int hw = mt*128+m, c0 = ks*64+k8*8;
  const float* xp = x + ((size_t)(b*256 + c0))*4096 + hw;
  const float* st = stats + (size_t)(b*256+c0)*2;
  uint4v o;
  #pragma unroll
  for (int j=0;j<8;j+=2){
    float v0 = (xp[(size_t)j*4096]     - st[j*2])   * st[j*2+1];
    float v1 = (xp[(size_t)(j+1)*4096] - st[j*2+2]) * st[j*2+3];
    o[j>>1] = f2bf(v0) | (f2bf(v1)<<16);
  }
  *(uint4v*)(apack + id*8) = o;
}

// ---------------- K3: fused gate/value/z GEMM ----------------
// Block = (b, mt): A-tile (xn, full K=256) resident in LDS; weight tiles streamed.
// Swapped MFMA: mfma(w_frag, x_frag) -> D[row=channel][col=position].
// Per thread: row = (lane>>4)*4+rr (4 consecutive channels), col = lane&15 (position).
// gv = (g+bg)*(v+bv) written bf16 in apack layout; z written fp32 [b][hw][128].
__global__ __launch_bounds__(512,1) void k_gvz(
    const unsigned short* __restrict__ Ap, const unsigned short* __restrict__ Wc,
    const float* __restrict__ biases,
    unsigned short* __restrict__ gvp, float* __restrict__ zbuf){
  extern __shared__ unsigned short sm[];           // A 32768 | B0 8192 | B1 8192 elems (96 KiB)
  unsigned short* As = sm;
  unsigned short* B0 = sm + 32768;
  unsigned short* B1 = sm + 40960;
  int bid = blockIdx.x; int b = bid>>5, mt = bid&31;
  const unsigned short* At = Ap + (size_t)(b*32+mt)*32768;
  int t = threadIdx.x, lane = t&63, wid = t>>6;
  int wr = wid>>1, wc = wid&1;    // wr: position quarter (32 rows), wc: channel half (64)
  // stage A (full K) + first weight chunk
  #pragma unroll
  for (int i=0;i<8;i++) gload16(At + (size_t)(i*512+t)*8, As + (size_t)(i*512+t)*8);
  #pragma unroll
  for (int i=0;i<2;i++) gload16(Wc + (size_t)(i*512+t)*8, B0 + (size_t)(i*512+t)*8);
  __syncthreads();

  f32x4 accg[4][2]={}, accv[4][2]={}, accz[4][2]={};
  const int ord[5] = {0,2,1,3,4};  // gate0, value0, gate1, value1, z

  #define CHUNKC(ACC, KS, BUF) \
    _Pragma("unroll") \
    for (int kf=0;kf<2;kf++){ \
      int k8l = kf*4 + (lane>>4); \
      short8 wf[4]; short8 xf[2]; \
      _Pragma("unroll") \
      for (int ci=0;ci<4;ci++) \
        wf[ci] = *(const short8*)&(BUF)[(size_t)(k8l*128 + wc*64 + ci*16 + (lane&15))*8]; \
      _Pragma("unroll") \
      for (int pj=0;pj<2;pj++) \
        xf[pj] = *(const short8*)&As[(size_t)(((KS)*8+k8l)*128 + wr*32 + pj*16 + (lane&15))*8]; \
      _Pragma("unroll") \
      for (int ci=0;ci<4;ci++) \
        _Pragma("unroll") \
        for (int pj=0;pj<2;pj++) \
          ACC[ci][pj] = __builtin_amdgcn_mfma_f32_16x16x32_bf16(wf[ci], xf[pj], ACC[ci][pj], 0,0,0); \
    }

  #pragma unroll
  for (int c=0;c<20;c++){
    if (c<19){
      const unsigned short* src = Wc + (size_t)ord[(c+1)>>2]*32768 + (size_t)((c+1)&3)*8192;
      unsigned short* dst = ((c+1)&1) ? B1 : B0;
      #pragma unroll
      for (int i=0;i<2;i++) gload16(src + (size_t)(i*512+t)*8, dst + (size_t)(i*512+t)*8);
    }
    int p = c>>2, ks = c&3;
    if (p==0||p==2){ if (c&1){ CHUNKC(accg, ks, B1) } else { CHUNKC(accg, ks, B0) } }
    else if (p==1||p==3){ if (c&1){ CHUNKC(accv, ks, B1) } else { CHUNKC(accv, ks, B0) } }
    else { if (c&1){ CHUNKC(accz, ks, B1) } else { CHUNKC(accz, ks, B0) } }
    if (c==7 || c==15){
      int np = c>>3;  // 0 or 1
      #pragma unroll
      for (int ci=0;ci<4;ci++){
        int cg = np*128 + wc*64 + ci*16 + ((lane>>4)<<2);  // global channel, mult of 4
        f32x4 bg = *(const f32x4*)&biases[cg];
        f32x4 bv = *(const f32x4*)&biases[256+cg];
        int ksO = cg>>6, k8O = (cg>>3)&7, j0 = cg&7;
        #pragma unroll
        for (int pj=0;pj<2;pj++){
          f32x4 pg = accg[ci][pj] + bg;
          f32x4 pv = accv[ci][pj] + bv;
          f32x4 pr = pg * pv;
          int m = wr*32 + pj*16 + (lane&15);
          size_t e = (((size_t)(b*32+mt)*4 + ksO)*8192) + (size_t)(k8O*128 + m)*8 + j0;
          uint2v pk;
          pk[0] = f2bf(pr[0]) | (f2bf(pr[1])<<16);
          pk[1] = f2bf(pr[2]) | (f2bf(pr[3])<<16);
          *(uint2v*)(gvp + e) = pk;
          accg[ci][pj] = (f32x4){0.f,0.f,0.f,0.f};
          accv[ci][pj] = (f32x4){0.f,0.f,0.f,0.f};
        }
      }
    }
    __syncthreads();
  }
  // z epilogue: zbuf[b][hw][128] fp32
  #pragma unroll
  for (int ci=0;ci<4;ci++){
    int ch = wc*64 + ci*16 + ((lane>>4)<<2);
    f32x4 bz = *(const f32x4*)&biases[512+ch];
    #pragma unroll
    for (int pj=0;pj<2;pj++){
      int m = wr*32 + pj*16 + (lane&15);
      f32x4 zv = accz[ci][pj] + bz;
      *(f32x4*)&zbuf[((size_t)b*4096 + mt*128 + m)*128 + ch] = zv;
    }
  }
  #undef CHUNKC
}

// ---------------- K4: proj GEMM: out[b][o][hw] = Wp @ V + bp ----------------
// Block = (b, mt): V-tile resident; W chunks streamed. mfma(v_frag, w_frag) -> D[row=hw][col=o].
__global__ __launch_bounds__(512,1) void k_proj(
    const unsigned short* __restrict__ Vp, const unsigned short* __restrict__ Wp,
    const float* __restrict__ biases, float* __restrict__ out){
  extern __shared__ unsigned short sm[];
  unsigned short* Vs = sm;
  unsigned short* B0 = sm + 32768;
  unsigned short* B1 = sm + 40960;
  int bid = blockIdx.x; int b = bid>>5, mt = bid&31;
  const unsigned short* Vt = Vp + (size_t)(b*32+mt)*32768;
  int t = threadIdx.x, lane = t&63, wid = t>>6;
  int rw = wid&1, rq = wid>>1;   // rw: hw half (64), rq: o quarter (32)
  #pragma unroll
  for (int i=0;i<8;i++) gload16(Vt + (size_t)(i*512+t)*8, Vs + (size_t)(i*512+t)*8);
  #pragma unroll
  for (int i=0;i<2;i++) gload16(Wp + (size_t)(i*512+t)*8, B0 + (size_t)(i*512+t)*8);
  __syncthreads();

  f32x4 acc[4][2]={};
  #pragma unroll
  for (int c=0;c<8;c++){
    if (c<7){
      const unsigned short* src = Wp + (size_t)(c+1)*8192;
      unsigned short* dst = ((c+1)&1) ? B1 : B0;
      #pragma unroll
      for (int i=0;i<2;i++) gload16(src + (size_t)(i*512+t)*8, dst + (size_t)(i*512+t)*8);
    }
    int ks = c&3;
    {
      const unsigned short* BUF = (c&1) ? B1 : B0;
      #pragma unroll
      for (int kf=0;kf<2;kf++){
        int k8l = kf*4 + (lane>>4);
        short8 vf[4]; short8 wf[2];
        #pragma unroll
        for (int hi=0;hi<4;hi++)
          vf[hi] = *(const short8*)&Vs[(size_t)((ks*8+k8l)*128 + rw*64 + hi*16 + (lane&15))*8];
        #pragma unroll
        for (int oj=0;oj<2;oj++)
          wf[oj] = *(const short8*)&BUF[(size_t)(k8l*128 + rq*32 + oj*16 + (lane&15))*8];
        #pragma unroll
        for (int hi=0;hi<4;hi++)
          #pragma unroll
          for (int oj=0;oj<2;oj++)
            acc[hi][oj] = __builtin_amdgcn_mfma_f32_16x16x32_bf16(vf[hi], wf[oj], acc[hi][oj], 0,0,0);
      }
    }
    if (c==3 || c==7){
      int oh = c>>2;
      #pragma unroll
      for (int oj=0;oj<2;oj++){
        int o = oh*128 + rq*32 + oj*16 + (lane&15);
        float bo = biases[640 + o];
        #pragma unroll
        for (int hi=0;hi<4;hi++){
          int hw = mt*128 + rw*64 + hi*16 + ((lane>>4)<<2);
          f32x4 v = acc[hi][oj] + (f32x4){bo,bo,bo,bo};
          *(f32x4*)&out[((size_t)b*256 + o)*4096 + hw] = v;
          acc[hi][oj] = (f32x4){0.f,0.f,0.f,0.f};
        }
      }
    }
    __syncthreads();
  }
}

// ---------------- K5: affine + 2D RoPE + q.k -> sim ----------------
__global__ __launch_bounds__(256) void k_sim(const float* __restrict__ zbuf,
    const float* __restrict__ gamma, const float* __restrict__ beta,
    float* __restrict__ sim){
  int pos = blockIdx.x*4 + (threadIdx.x>>6);
  int lane = threadIdx.x & 63;
  int b = pos>>12, hw = pos&4095;
  int h = hw>>6, w = hw&63;
  f32x2 z2 = *(const f32x2*)(zbuf + ((size_t)b*4096+hw)*128 + 2*lane);
  f32x2 g0 = *(const f32x2*)(gamma + 2*lane);
  f32x2 g1 = *(const f32x2*)(gamma + 128 + 2*lane);
  f32x2 b0 = *(const f32x2*)(beta + 2*lane);
  f32x2 b1 = *(const f32x2*)(beta + 128 + 2*lane);
  float q0 = z2[0]*g0[0] + b0[0], q1 = z2[1]*g0[1] + b0[1];
  float k0 = z2[0]*g1[0] + b1[0], k1 = z2[1]*g1[1] + b1[1];
  float fidx = (float)(lane&31);
  float inv = expf(fidx * -0.28782313662425574f);  // ln(10000)/32
  float p = (lane<32) ? (float)h : (float)w;
  float ang = p*inv, sn, cs;
  sincosf(ang, &sn, &cs);
  float q0r = q0*cs - q1*sn, q1r = q0*sn + q1*cs;
  float k0r = k0*cs - k1*sn, k1r = k0*sn + k1*cs;
  float part = q0r*k0r + q1r*k1r;
  #pragma unroll
  for (int off=32; off; off>>=1) part += __shfl_xor(part, off);
  if (lane==0) sim[pos] = part * 0.08838834764831845f;  // 1/sqrt(128)
}

// ---------------- K6: per-batch softmax over 4096 -> A (fp32, final slot) ----------------
__global__ __launch_bounds__(256) void k_softmax(const float* __restrict__ sim, float* __restrict__ A){
  int b = blockIdx.x, t = threadIdx.x, lane = t&63, wid = t>>6;
  const f32x4* s4 = (const f32x4*)(sim + (size_t)b*4096);
  f32x4 v[4];
  float mx = -3.4e38f;
  #pragma unroll
  for (int i=0;i<4;i++){
    v[i] = s4[i*256+t];
    #pragma unroll
    for (int w=0;w<4;w++) mx = fmaxf(mx, v[i][w]);
  }
  #pragma unroll
  for (int off=32; off; off>>=1) mx = fmaxf(mx, __shfl_xor(mx, off));
  __shared__ float sr1[4], sr2[4];
  if (lane==0) sr1[wid]=mx;
  __syncthreads();
  mx = fmaxf(fmaxf(sr1[0],sr1[1]), fmaxf(sr1[2],sr1[3]));
  float sum=0.f;
  #pragma unroll
  for (int i=0;i<4;i++)
    #pragma unroll
    for (int w=0;w<4;w++){ float e = expf(v[i][w]-mx); v[i][w]=e; sum+=e; }
  #pragma unroll
  for (int off=32; off; off>>=1) sum += __shfl_xor(sum, off);
  if (lane==0) sr2[wid]=sum;
  __syncthreads();
  sum = sr2[0]+sr2[1]+sr2[2]+sr2[3];
  float invs = 1.0f/sum;
  f32x4* Ab = (f32x4*)(A + (size_t)b*4096);
  #pragma unroll
  for (int i=0;i<4;i++){
    f32x4 a;
    #pragma unroll
    for (int w=0;w<4;w++) a[w] = v[i][w]*invs;
    Ab[i*256+t] = a;
  }
}

// ---------------- K7: V = A*gv + xn, bf16 in-place into apack ----------------
__global__ __launch_bounds__(256) void k_vcompute(unsigned short* __restrict__ apack,
    const unsigned short* __restrict__ gvp, const float* __restrict__ A){
  size_t id = (size_t)blockIdx.x*256 + threadIdx.x;
  int m=(int)(id&127), mt=(int)(id>>12)&31, b=(int)(id>>17);
  int hw = mt*128+m;
  float a = A[(size_t)b*4096 + hw];
  uint4v gg = *(const uint4v*)(gvp + id*8);
  uint4v xx = *(const uint4v*)(apack + id*8);
  uint4v o;
  #pragma unroll
  for (int w=0; w<4; w++){
    float gA = bf2f((unsigned short)(gg[w]&0xffff)), gBv = bf2f((unsigned short)(gg[w]>>16));
    float xA = bf2f((unsigned short)(xx[w]&0xffff)), xB = bf2f((unsigned short)(xx[w]>>16));
    o[w] = f2bf(a*gA + xA) | (f2bf(a*gBv + xB)<<16);
  }
  *(uint4v*)(apack + id*8) = o;
}

// ---------------- launch ----------------
extern "C" void kernel_launch(void* const* d_in, const int* in_sizes, int n_in,
                              void* d_out, int out_size, void* d_ws, size_t ws_size,
                              hipStream_t stream){
  const float* x  = (const float*)d_in[0];
  const float* gW = (const float*)d_in[1];
  const float* gB = (const float*)d_in[2];
  const float* vW = (const float*)d_in[3];
  const float* vB = (const float*)d_in[4];
  const float* zW = (const float*)d_in[5];
  const float* zB = (const float*)d_in[6];
  const float* gm = (const float*)d_in[7];
  const float* bt = (const float*)d_in[8];
  const float* pW = (const float*)d_in[9];
  const float* pB = (const float*)d_in[10];

  char* ws = (char*)d_ws;
  float* stats          = (float*)(ws + 0);                  //  32 KB
  float* biases         = (float*)(ws + 32768);              //  3.5 KB
  float* sim            = (float*)(ws + 40960);              // 256 KB
  unsigned short* wcat  = (unsigned short*)(ws + 303104);    // 320 KB bf16
  unsigned short* proj  = (unsigned short*)(ws + 958464);    // 128 KB bf16
  unsigned short* apack = (unsigned short*)(ws + 2097152);   // 33.5 MB bf16 (xn, then V in-place)
  // total ws use: 35,651,584 B

  float* out = (float*)d_out;
  unsigned short* gvp = (unsigned short*)out;        // 33.5 MB bf16, apack layout (scratch in out)
  float* zbuf = out + 8388608;                        // 33.5 MB fp32 (scratch in out)
  float* A    = out + 16777216;                       // final A slot (16x64x64 fp32)

  hipLaunchKernelGGL(k_pack_w,  dim3(112),  dim3(256), 0, stream, gW, vW, zW, pW, gB, vB, zB, pB, wcat, proj, biases);
  hipLaunchKernelGGL(k_stats,   dim3(4096), dim3(256), 0, stream, x, stats);
  hipLaunchKernelGGL(k_xn_pack, dim3(8192), dim3(256), 0, stream, x, stats, apack);
  hipLaunchKernelGGL(k_gvz,     dim3(512),  dim3(512), 98304, stream, apack, wcat, biases, gvp, zbuf);
  hipLaunchKernelGGL(k_sim,     dim3(16384), dim3(256), 0, stream, zbuf, gm, bt, sim);
  hipLaunchKernelGGL(k_softmax, dim3(16),    dim3(256), 0, stream, sim, A);
  hipLaunchKernelGGL(k_vcompute,dim3(8192),  dim3(256), 0, stream, apack, gvp, A);
  hipLaunchKernelGGL(k_proj,    dim3(512),  dim3(512), 98304, stream, apack, proj, biases, out);
  (void)in_sizes; (void)n_in; (void)out_size; (void)ws_size;
}

// Round 6
// 115.973 us; speedup vs baseline: 1.6174x; 1.1650x over previous
//
#include <hip/hip_runtime.h>
#include <hip/hip_bf16.h>
#include <cstdint>
#include <cstddef>

// GAU fused pipeline. fp32 I/O; bf16 MFMA internally.
// B=16 C=256 H=W=64 (HW=4096) S=128 O=256. ws: 66 MiB; zbuf staged in d_out.

typedef __attribute__((ext_vector_type(8))) short short8;     // 8 bf16 MFMA frag
typedef __attribute__((ext_vector_type(4))) float f32x4;
typedef __attribute__((ext_vector_type(2))) float f32x2;
typedef __attribute__((ext_vector_type(4))) unsigned int uint4v;
typedef __attribute__((ext_vector_type(2))) unsigned int uint2v;

#define DI __device__ __forceinline__

DI unsigned int f2bf(float f){ unsigned int i; __builtin_memcpy(&i,&f,4); return (i + 0x7fffu + ((i>>16)&1u))>>16; }
DI float bf2f(unsigned short u){ unsigned int i = ((unsigned int)u)<<16; float f; __builtin_memcpy(&f,&i,4); return f; }

DI void gload16(const void* g, void* l){
  __builtin_amdgcn_global_load_lds((const __attribute__((address_space(1))) void*)g,
                                   (__attribute__((address_space(3))) void*)l, 16, 0, 0);
}

// ---------------- K0: pack weights fp32->bf16 + biases ----------------
// wcat: [nt(5)][ks(4)][k8(8)][n(128)][8]  (o=nt*128+n, c=ks*64+k8*8+j; nt 0-1 gate, 2-3 value, 4 z)
// proj: [oh(2)][ks(4)][k8(8)][o(128)][8]
__global__ __launch_bounds__(256) void k_pack_w(
    const float* __restrict__ gW, const float* __restrict__ vW,
    const float* __restrict__ zW, const float* __restrict__ pW,
    const float* __restrict__ gB, const float* __restrict__ vB,
    const float* __restrict__ zB, const float* __restrict__ pB,
    unsigned short* __restrict__ wcat, unsigned short* __restrict__ proj,
    float* __restrict__ biases){
  int id = blockIdx.x*256 + threadIdx.x;
  if (id < 20480){
    int n=id&127, k8=(id>>7)&7, ks=(id>>10)&3, nt=id>>12;
    int o = nt*128+n, c0 = ks*64+k8*8;
    const float* src = (o<256) ? gW + (size_t)o*256 + c0
                      : (o<512) ? vW + (size_t)(o-256)*256 + c0
                      :           zW + (size_t)(o-512)*256 + c0;
    f32x4 a = *(const f32x4*)src, b = *(const f32x4*)(src+4);
    uint4v ov;
    ov[0] = f2bf(a[0]) | (f2bf(a[1])<<16);
    ov[1] = f2bf(a[2]) | (f2bf(a[3])<<16);
    ov[2] = f2bf(b[0]) | (f2bf(b[1])<<16);
    ov[3] = f2bf(b[2]) | (f2bf(b[3])<<16);
    *(uint4v*)(wcat + (size_t)id*8) = ov;
  } else if (id < 28672){
    int q = id - 20480;
    int m=q&127, k8=(q>>7)&7, ks=(q>>10)&3, mt=q>>12;
    int o = mt*128+m, c0 = ks*64+k8*8;
    const float* src = pW + (size_t)o*256 + c0;
    f32x4 a = *(const f32x4*)src, b = *(const f32x4*)(src+4);
    uint4v ov;
    ov[0] = f2bf(a[0]) | (f2bf(a[1])<<16);
    ov[1] = f2bf(a[2]) | (f2bf(a[3])<<16);
    ov[2] = f2bf(b[0]) | (f2bf(b[1])<<16);
    ov[3] = f2bf(b[2]) | (f2bf(b[3])<<16);
    *(uint4v*)(proj + (size_t)q*8) = ov;
  }
  if (id < 640) biases[id] = id<256 ? gB[id] : id<512 ? vB[id-256] : zB[id-512];
  if (id < 256) biases[640+id] = pB[id];
}

// ---------------- K1: per-(b,c) mean / rstd over 4096 ----------------
__global__ __launch_bounds__(256) void k_stats(const float* __restrict__ x, float* __restrict__ stats){
  int bc = blockIdx.x, t = threadIdx.x, lane = t&63, wid = t>>6;
  const f32x4* row = (const f32x4*)(x + (size_t)bc*4096);
  float s=0.f, q=0.f;
  #pragma unroll
  for (int i=0;i<4;i++){
    f32x4 v = row[i*256+t];
    #pragma unroll
    for (int w=0;w<4;w++){ s += v[w]; q += v[w]*v[w]; }
  }
  #pragma unroll
  for (int off=32; off; off>>=1){ s += __shfl_xor(s,off); q += __shfl_xor(q,off); }
  __shared__ float r1[4], r2[4];
  if (lane==0){ r1[wid]=s; r2[wid]=q; }
  __syncthreads();
  if (t==0){
    float S=r1[0]+r1[1]+r1[2]+r1[3], Q=r2[0]+r2[1]+r2[2]+r2[3];
    float mu = S*(1.0f/4096.0f);
    float var = Q*(1.0f/4096.0f) - mu*mu;
    stats[bc*2]   = mu;
    stats[bc*2+1] = rsqrtf(var + 1e-5f);
  }
}

// ---------------- K2: normalize + pack xn (bf16) ----------------
// apack: [b(16)][mt(32)][ks(4)][k8(8)][m(128)][8], elem = xn[b][c=ks*64+k8*8+j][hw=mt*128+m]
__global__ __launch_bounds__(256) void k_xn_pack(const float* __restrict__ x,
    const float* __restrict__ stats, unsigned short* __restrict__ apack){
  size_t id = (size_t)blockIdx.x*256 + threadIdx.x;
  int m=(int)(id&127), k8=(int)(id>>7)&7, ks=(int)(id>>10)&3, mt=(int)(id>>12)&31, b=(int)(id>>17);
  int hw = mt*128+m, c0 = ks*64+k8*8;
  const float* xp = x + ((size_t)(b*256 + c0))*4096 + hw;
  const float* st = stats + (size_t)(b*256+c0)*2;
  uint4v o;
  #pragma unroll
  for (int j=0;j<8;j+=2){
    float v0 = (xp[(size_t)j*4096]     - st[j*2])   * st[j*2+1];
    float v1 = (xp[(size_t)(j+1)*4096] - st[j*2+2]) * st[j*2+3];
    o[j>>1] = f2bf(v0) | (f2bf(v1)<<16);
  }
  *(uint4v*)(apack + id*8) = o;
}

// ---------------- K3: fused (gate*value) + z GEMM ----------------
// Grid 16 x 5 x 32 (XCD-swizzled). Block p<4: computes channels [p*64,p*64+64) of BOTH
// gate and value for a 128-hw tile; epilogue writes product bf16 into gvpack (apack layout).
// Block p==4: z (128 ch) with LDS-transposed fp32 write to zbuf[b][hw][128].
// LDS W-slot layout: [k8][slot(128)][8], slot<64 = gate-ch p*64+slot, slot>=64 = value-ch p*64+(slot-64).
__global__ __launch_bounds__(256,2) void k_gvzf(
    const unsigned short* __restrict__ Ap, const unsigned short* __restrict__ Wc,
    const float* __restrict__ biases,
    unsigned short* __restrict__ gvp, float* __restrict__ zbuf){
  __shared__ alignas(16) unsigned short lds[2][2][8192];   // [buf][W/X][16KB]
  int orig = blockIdx.x;
  int wg = (orig&7)*320 + (orig>>3);           // bijective XCD swizzle (2560%8==0)
  int b = wg/160; int r = wg - b*160; int p = r>>5; int mt = r&31;
  const unsigned short* Xt = Ap + (size_t)(b*32+mt)*32768;
  int t = threadIdx.x, lane = t&63;
  int wo = (t>>6)>>1, wm = (t>>6)&1;

  #define STAGEGV(buf, kss) do{ \
    _Pragma("unroll") \
    for (int i_=0;i_<4;i_++){ \
      int idx_ = i_*256 + t; \
      int k8_ = idx_>>7, slot_ = idx_&127; \
      int half_ = slot_>>6, sl_ = slot_&63; \
      int nt_, n_; \
      if (p<4){ nt_ = (p>>1) + half_*2; n_ = ((p&1)<<6) | sl_; } \
      else    { nt_ = 4; n_ = slot_; } \
      gload16(Wc + ((size_t)(nt_*4+(kss)))*8192 + (size_t)(k8_*128+n_)*8, &lds[buf][0][(size_t)idx_*8]); \
      gload16(Xt + (size_t)(kss)*8192 + (size_t)idx_*8, &lds[buf][1][(size_t)idx_*8]); \
    } \
  }while(0)

  f32x4 accg[2][4]={}, accv[2][4]={};

  #define CGV(buf) do{ \
    _Pragma("unroll") \
    for (int kf_=0;kf_<2;kf_++){ \
      int k8l_ = kf_*4 + (lane>>4); \
      short8 wg_[2], wv_[2], xf_[4]; \
      _Pragma("unroll") for (int ci_=0;ci_<2;ci_++){ \
        int sg_ = wo*32 + ci_*16 + (lane&15); \
        wg_[ci_] = *(const short8*)&lds[buf][0][(size_t)(k8l_*128 + sg_)*8]; \
        wv_[ci_] = *(const short8*)&lds[buf][0][(size_t)(k8l_*128 + 64 + sg_)*8]; } \
      _Pragma("unroll") for (int mj_=0;mj_<4;mj_++) \
        xf_[mj_] = *(const short8*)&lds[buf][1][(size_t)(k8l_*128 + wm*64 + mj_*16 + (lane&15))*8]; \
      _Pragma("unroll") for (int ci_=0;ci_<2;ci_++) \
        _Pragma("unroll") for (int mj_=0;mj_<4;mj_++){ \
          accg[ci_][mj_] = __builtin_amdgcn_mfma_f32_16x16x32_bf16(wg_[ci_], xf_[mj_], accg[ci_][mj_],0,0,0); \
          accv[ci_][mj_] = __builtin_amdgcn_mfma_f32_16x16x32_bf16(wv_[ci_], xf_[mj_], accv[ci_][mj_],0,0,0); } \
    } \
  }while(0)

  STAGEGV(0,0);
  __syncthreads();
  #pragma unroll
  for (int ks=0; ks<4; ++ks){
    int cur = ks&1;
    if (ks<3) STAGEGV(cur^1, ks+1);
    CGV(cur);
    __syncthreads();
  }

  if (p<4){
    #pragma unroll
    for (int ci=0;ci<2;ci++){
      int c = p*64 + wo*32 + ci*16 + ((lane>>4)<<2);
      f32x4 bg = *(const f32x4*)&biases[c];
      f32x4 bv = *(const f32x4*)&biases[256+c];
      int ksO = c>>6, k8O = (c>>3)&7, j0 = c&7;
      size_t base = ((size_t)(b*32+mt)*4 + ksO)*8192 + (size_t)(k8O*128)*8 + j0;
      #pragma unroll
      for (int mj=0;mj<4;mj++){
        int m = wm*64 + mj*16 + (lane&15);
        f32x4 pg = accg[ci][mj] + bg;
        f32x4 pv = accv[ci][mj] + bv;
        uint2v pk;
        pk[0] = f2bf(pg[0]*pv[0]) | (f2bf(pg[1]*pv[1])<<16);
        pk[1] = f2bf(pg[2]*pv[2]) | (f2bf(pg[3]*pv[3])<<16);
        *(uint2v*)(gvp + base + (size_t)m*8) = pk;
      }
    }
  } else {
    // z: LDS transpose -> zbuf[b][hw][128] fp32, coalesced
    float* fl = (float*)&lds[0][0][0];
    #pragma unroll
    for (int ci=0;ci<2;ci++){
      int cq0 = wo*32 + ci*16 + ((lane>>4)<<2);
      f32x4 bz0 = *(const f32x4*)&biases[512+cq0];
      f32x4 bz1 = *(const f32x4*)&biases[512+64+cq0];
      #pragma unroll
      for (int mj=0;mj<4;mj++){
        int m = wm*64 + mj*16 + (lane&15);
        int swz = ((m>>2)&31)<<2;
        f32x4 zlo = accg[ci][mj] + bz0;
        f32x4 zhi = accv[ci][mj] + bz1;
        *(f32x4*)&fl[(size_t)m*128 + (cq0 ^ swz)] = zlo;
        *(f32x4*)&fl[(size_t)m*128 + ((cq0+64) ^ swz)] = zhi;
      }
    }
    __syncthreads();
    #pragma unroll
    for (int it=0; it<16; it++){
      int gid = it*256 + t;
      int hw_r = gid>>5, cq = (gid&31)<<2;
      f32x4 v = *(const f32x4*)&fl[(size_t)hw_r*128 + (cq ^ (((hw_r>>2)&31)<<2))];
      *(f32x4*)&zbuf[((size_t)(b*4096 + mt*128 + hw_r))*128 + cq] = v;
    }
  }
  #undef STAGEGV
  #undef CGV
}

// ---------------- K4: proj GEMM with fused V = A*gv + xn staging ----------------
// Grid 16 x 2 x 32 (XCD-swizzled). out[b][o][hw] = Wp @ V + bp, epilogue LDS-transposed.
__global__ __launch_bounds__(256,2) void k_projf(
    const unsigned short* __restrict__ gvp, const unsigned short* __restrict__ Xp,
    const unsigned short* __restrict__ Wp, const float* __restrict__ biases,
    const float* __restrict__ A, float* __restrict__ out){
  __shared__ alignas(16) unsigned short lds[2][2][8192];
  int orig = blockIdx.x;
  int wg = (orig&7)*128 + (orig>>3);           // bijective (1024%8==0)
  int b = wg>>6; int r = wg&63; int ot = r>>5; int mt = r&31;
  int t = threadIdx.x, lane = t&63;
  int wo = (t>>6)>>1, wm = (t>>6)&1;
  size_t tbase = (size_t)(b*32+mt)*32768;
  float a = A[(size_t)b*4096 + mt*128 + (t&127)];
  uint4v Gr[4], Xr[4];

  #define LOADV(kss) do{ _Pragma("unroll") for (int i_=0;i_<4;i_++){ \
      Gr[i_] = *(const uint4v*)(gvp + tbase + (size_t)(kss)*8192 + (size_t)(i_*256+t)*8); \
      Xr[i_] = *(const uint4v*)(Xp  + tbase + (size_t)(kss)*8192 + (size_t)(i_*256+t)*8); } }while(0)

  #define WRITEV(buf) do{ _Pragma("unroll") for (int i_=0;i_<4;i_++){ \
      uint4v g_=Gr[i_], x_=Xr[i_]; uint4v o_; \
      _Pragma("unroll") for (int w_=0;w_<4;w_++){ \
        float gA_=bf2f((unsigned short)(g_[w_]&0xffff)), gB_=bf2f((unsigned short)(g_[w_]>>16)); \
        float xA_=bf2f((unsigned short)(x_[w_]&0xffff)), xB_=bf2f((unsigned short)(x_[w_]>>16)); \
        o_[w_] = f2bf(a*gA_+xA_) | (f2bf(a*gB_+xB_)<<16); } \
      *(uint4v*)&lds[buf][1][(size_t)(i_*256+t)*8] = o_; } }while(0)

  #define STAGEW(buf, kss) do{ _Pragma("unroll") for (int i_=0;i_<4;i_++){ \
      int idx_ = i_*256+t; \
      gload16(Wp + (size_t)(ot*4+(kss))*8192 + (size_t)idx_*8, &lds[buf][0][(size_t)idx_*8]); } }while(0)

  f32x4 acc[4][4]={};

  #define CPJ(buf) do{ \
    _Pragma("unroll") for (int kf_=0;kf_<2;kf_++){ \
      int k8l_ = kf_*4 + (lane>>4); \
      short8 wf_[4], vf_[4]; \
      _Pragma("unroll") for (int ci_=0;ci_<4;ci_++) \
        wf_[ci_] = *(const short8*)&lds[buf][0][(size_t)(k8l_*128 + wo*64 + ci_*16 + (lane&15))*8]; \
      _Pragma("unroll") for (int mj_=0;mj_<4;mj_++) \
        vf_[mj_] = *(const short8*)&lds[buf][1][(size_t)(k8l_*128 + wm*64 + mj_*16 + (lane&15))*8]; \
      _Pragma("unroll") for (int ci_=0;ci_<4;ci_++) \
        _Pragma("unroll") for (int mj_=0;mj_<4;mj_++) \
          acc[ci_][mj_] = __builtin_amdgcn_mfma_f32_16x16x32_bf16(wf_[ci_], vf_[mj_], acc[ci_][mj_],0,0,0); \
    } }while(0)

  LOADV(0); STAGEW(0,0); WRITEV(0);
  __syncthreads();
  #pragma unroll
  for (int ks=0; ks<4; ++ks){
    int cur = ks&1;
    if (ks<3){ LOADV(ks+1); STAGEW(cur^1, ks+1); }
    CPJ(cur);
    if (ks<3) WRITEV(cur^1);
    __syncthreads();
  }

  // epilogue: acc (rows=o, cols=hw) -> LDS [hw][o^swz] -> coalesced out rows
  float* fl = (float*)&lds[0][0][0];
  #pragma unroll
  for (int ci=0;ci<4;ci++){
    int oq = wo*64 + ci*16 + ((lane>>4)<<2);
    #pragma unroll
    for (int mj=0;mj<4;mj++){
      int m = wm*64 + mj*16 + (lane&15);
      *(f32x4*)&fl[(size_t)m*128 + (oq ^ (((m>>2)&31)<<2))] = acc[ci][mj];
    }
  }
  __syncthreads();
  #pragma unroll
  for (int it=0; it<16; it++){
    int gid = it*256 + t;
    int o_r = gid>>5, hq = (gid&31)<<2;
    float bo = biases[640 + ot*128 + o_r];
    f32x4 vo;
    #pragma unroll
    for (int k=0;k<4;k++){
      int m2 = hq+k;
      vo[k] = fl[(size_t)m2*128 + (o_r ^ (((m2>>2)&31)<<2))] + bo;
    }
    *(f32x4*)&out[((size_t)(b*256 + ot*128 + o_r))*4096 + mt*128 + hq] = vo;
  }
  #undef LOADV
  #undef WRITEV
  #undef STAGEW
  #undef CPJ
}

// ---------------- K5: affine + 2D RoPE + q.k -> sim ----------------
__global__ __launch_bounds__(256) void k_sim(const float* __restrict__ zbuf,
    const float* __restrict__ gamma, const float* __restrict__ beta,
    float* __restrict__ sim){
  int pos = blockIdx.x*4 + (threadIdx.x>>6);
  int lane = threadIdx.x & 63;
  int b = pos>>12, hw = pos&4095;
  int h = hw>>6, w = hw&63;
  f32x2 z2 = *(const f32x2*)(zbuf + ((size_t)b*4096+hw)*128 + 2*lane);
  f32x2 g0 = *(const f32x2*)(gamma + 2*lane);
  f32x2 g1 = *(const f32x2*)(gamma + 128 + 2*lane);
  f32x2 b0 = *(const f32x2*)(beta + 2*lane);
  f32x2 b1 = *(const f32x2*)(beta + 128 + 2*lane);
  float q0 = z2[0]*g0[0] + b0[0], q1 = z2[1]*g0[1] + b0[1];
  float k0 = z2[0]*g1[0] + b1[0], k1 = z2[1]*g1[1] + b1[1];
  float fidx = (float)(lane&31);
  float inv = expf(fidx * -0.28782313662425574f);  // ln(10000)/32
  float p = (lane<32) ? (float)h : (float)w;
  float ang = p*inv, sn, cs;
  sincosf(ang, &sn, &cs);
  float q0r = q0*cs - q1*sn, q1r = q0*sn + q1*cs;
  float k0r = k0*cs - k1*sn, k1r = k0*sn + k1*cs;
  float part = q0r*k0r + q1r*k1r;
  #pragma unroll
  for (int off=32; off; off>>=1) part += __shfl_xor(part, off);
  if (lane==0) sim[pos] = part * 0.08838834764831845f;  // 1/sqrt(128)
}

// ---------------- K6: per-batch softmax over 4096 -> A ----------------
__global__ __launch_bounds__(256) void k_softmax(const float* __restrict__ sim, float* __restrict__ A){
  int b = blockIdx.x, t = threadIdx.x, lane = t&63, wid = t>>6;
  const f32x4* s4 = (const f32x4*)(sim + (size_t)b*4096);
  f32x4 v[4];
  float mx = -3.4e38f;
  #pragma unroll
  for (int i=0;i<4;i++){
    v[i] = s4[i*256+t];
    #pragma unroll
    for (int w=0;w<4;w++) mx = fmaxf(mx, v[i][w]);
  }
  #pragma unroll
  for (int off=32; off; off>>=1) mx = fmaxf(mx, __shfl_xor(mx, off));
  __shared__ float sr1[4], sr2[4];
  if (lane==0) sr1[wid]=mx;
  __syncthreads();
  mx = fmaxf(fmaxf(sr1[0],sr1[1]), fmaxf(sr1[2],sr1[3]));
  float sum=0.f;
  #pragma unroll
  for (int i=0;i<4;i++)
    #pragma unroll
    for (int w=0;w<4;w++){ float e = expf(v[i][w]-mx); v[i][w]=e; sum+=e; }
  #pragma unroll
  for (int off=32; off; off>>=1) sum += __shfl_xor(sum, off);
  if (lane==0) sr2[wid]=sum;
  __syncthreads();
  sum = sr2[0]+sr2[1]+sr2[2]+sr2[3];
  float invs = 1.0f/sum;
  f32x4* Ab = (f32x4*)(A + (size_t)b*4096);
  #pragma unroll
  for (int i=0;i<4;i++){
    f32x4 a;
    #pragma unroll
    for (int w=0;w<4;w++) a[w] = v[i][w]*invs;
    Ab[i*256+t] = a;
  }
}

// ---------------- launch ----------------
extern "C" void kernel_launch(void* const* d_in, const int* in_sizes, int n_in,
                              void* d_out, int out_size, void* d_ws, size_t ws_size,
                              hipStream_t stream){
  const float* x  = (const float*)d_in[0];
  const float* gW = (const float*)d_in[1];
  const float* gB = (const float*)d_in[2];
  const float* vW = (const float*)d_in[3];
  const float* vB = (const float*)d_in[4];
  const float* zW = (const float*)d_in[5];
  const float* zB = (const float*)d_in[6];
  const float* gm = (const float*)d_in[7];
  const float* bt = (const float*)d_in[8];
  const float* pW = (const float*)d_in[9];
  const float* pB = (const float*)d_in[10];

  char* ws = (char*)d_ws;
  float* stats           = (float*)(ws + 0);                  //  32 KB
  float* biases          = (float*)(ws + 32768);              //  3.5 KB
  float* sim             = (float*)(ws + 40960);              // 256 KB
  unsigned short* wcat   = (unsigned short*)(ws + 303104);    // 320 KB bf16
  unsigned short* proj   = (unsigned short*)(ws + 958464);    // 128 KB bf16
  unsigned short* apack  = (unsigned short*)(ws + 2097152);   // 33.5 MB bf16 (xn)
  unsigned short* gvpack = (unsigned short*)(ws + 35651584);  // 33.5 MB bf16 -> total 69,206,016 B

  float* out  = (float*)d_out;
  float* zbuf = out + 8388608;   // 33.5 MB fp32 scratch in out-region (consumed before proj)
  float* A    = out + 16777216;  // final A slot (16x64x64 fp32)

  hipLaunchKernelGGL(k_pack_w,  dim3(112),  dim3(256), 0, stream, gW, vW, zW, pW, gB, vB, zB, pB, wcat, proj, biases);
  hipLaunchKernelGGL(k_stats,   dim3(4096), dim3(256), 0, stream, x, stats);
  hipLaunchKernelGGL(k_xn_pack, dim3(8192), dim3(256), 0, stream, x, stats, apack);
  hipLaunchKernelGGL(k_gvzf,    dim3(2560), dim3(256), 0, stream, apack, wcat, biases, gvpack, zbuf);
  hipLaunchKernelGGL(k_sim,     dim3(16384), dim3(256), 0, stream, zbuf, gm, bt, sim);
  hipLaunchKernelGGL(k_softmax, dim3(16),    dim3(256), 0, stream, sim, A);
  hipLaunchKernelGGL(k_projf,   dim3(1024), dim3(256), 0, stream, gvpack, apack, proj, biases, A, out);
  (void)in_sizes; (void)n_in; (void)out_size; (void)ws_size;
}

// Round 7
// 98.449 us; speedup vs baseline: 1.9054x; 1.1780x over previous
//
#include <hip/hip_runtime.h>
#include <hip/hip_bf16.h>
#include <cstdint>
#include <cstddef>

// GAU fused pipeline. fp32 I/O; bf16 MFMA internally.
// B=16 C=256 H=W=64 (HW=4096) S=128 O=256. ws: 66 MiB.
// RoPE eliminated algebraically: sim = q.k at equal positions is rotation-invariant.

typedef __attribute__((ext_vector_type(8))) short short8;     // 8 bf16 MFMA frag
typedef __attribute__((ext_vector_type(4))) float f32x4;
typedef __attribute__((ext_vector_type(2))) float f32x2;
typedef __attribute__((ext_vector_type(4))) unsigned int uint4v;
typedef __attribute__((ext_vector_type(2))) unsigned int uint2v;

#define DI __device__ __forceinline__

DI unsigned int f2bf(float f){ unsigned int i; __builtin_memcpy(&i,&f,4); return (i + 0x7fffu + ((i>>16)&1u))>>16; }
DI float bf2f(unsigned short u){ unsigned int i = ((unsigned int)u)<<16; float f; __builtin_memcpy(&f,&i,4); return f; }
DI unsigned int pk2bf(float lo, float hi){
  float2 f2; f2.x = lo; f2.y = hi;
  __hip_bfloat162 h = __float22bfloat162_rn(f2);
  unsigned int u; __builtin_memcpy(&u, &h, 4); return u;
}

DI void gload16(const void* g, void* l){
  __builtin_amdgcn_global_load_lds((const __attribute__((address_space(1))) void*)g,
                                   (__attribute__((address_space(3))) void*)l, 16, 0, 0);
}

// ---------------- K0: pack weights fp32->bf16 + biases ----------------
// wcat: [nt(5)][ks(4)][k8(8)][n(128)][8]  (o=nt*128+n, c=ks*64+k8*8+j; nt 0-1 gate, 2-3 value, 4 z)
// proj: [oh(2)][ks(4)][k8(8)][o(128)][8]
__global__ __launch_bounds__(256) void k_pack_w(
    const float* __restrict__ gW, const float* __restrict__ vW,
    const float* __restrict__ zW, const float* __restrict__ pW,
    const float* __restrict__ gB, const float* __restrict__ vB,
    const float* __restrict__ zB, const float* __restrict__ pB,
    unsigned short* __restrict__ wcat, unsigned short* __restrict__ proj,
    float* __restrict__ biases){
  int id = blockIdx.x*256 + threadIdx.x;
  if (id < 20480){
    int n=id&127, k8=(id>>7)&7, ks=(id>>10)&3, nt=id>>12;
    int o = nt*128+n, c0 = ks*64+k8*8;
    const float* src = (o<256) ? gW + (size_t)o*256 + c0
                      : (o<512) ? vW + (size_t)(o-256)*256 + c0
                      :           zW + (size_t)(o-512)*256 + c0;
    f32x4 a = *(const f32x4*)src, b = *(const f32x4*)(src+4);
    uint4v ov;
    ov[0] = pk2bf(a[0],a[1]); ov[1] = pk2bf(a[2],a[3]);
    ov[2] = pk2bf(b[0],b[1]); ov[3] = pk2bf(b[2],b[3]);
    *(uint4v*)(wcat + (size_t)id*8) = ov;
  } else if (id < 28672){
    int q = id - 20480;
    int m=q&127, k8=(q>>7)&7, ks=(q>>10)&3, mt=q>>12;
    int o = mt*128+m, c0 = ks*64+k8*8;
    const float* src = pW + (size_t)o*256 + c0;
    f32x4 a = *(const f32x4*)src, b = *(const f32x4*)(src+4);
    uint4v ov;
    ov[0] = pk2bf(a[0],a[1]); ov[1] = pk2bf(a[2],a[3]);
    ov[2] = pk2bf(b[0],b[1]); ov[3] = pk2bf(b[2],b[3]);
    *(uint4v*)(proj + (size_t)q*8) = ov;
  }
  if (id < 640) biases[id] = id<256 ? gB[id] : id<512 ? vB[id-256] : zB[id-512];
  if (id < 256) biases[640+id] = pB[id];
}

// ---------------- K1: per-(b,c) mean / rstd over 4096 ----------------
__global__ __launch_bounds__(256) void k_stats(const float* __restrict__ x, float* __restrict__ stats){
  int bc = blockIdx.x, t = threadIdx.x, lane = t&63, wid = t>>6;
  const f32x4* row = (const f32x4*)(x + (size_t)bc*4096);
  float s=0.f, q=0.f;
  #pragma unroll
  for (int i=0;i<4;i++){
    f32x4 v = row[i*256+t];
    #pragma unroll
    for (int w=0;w<4;w++){ s += v[w]; q += v[w]*v[w]; }
  }
  #pragma unroll
  for (int off=32; off; off>>=1){ s += __shfl_xor(s,off); q += __shfl_xor(q,off); }
  __shared__ float r1[4], r2[4];
  if (lane==0){ r1[wid]=s; r2[wid]=q; }
  __syncthreads();
  if (t==0){
    float S=r1[0]+r1[1]+r1[2]+r1[3], Q=r2[0]+r2[1]+r2[2]+r2[3];
    float mu = S*(1.0f/4096.0f);
    float var = Q*(1.0f/4096.0f) - mu*mu;
    stats[bc*2]   = mu;
    stats[bc*2+1] = rsqrtf(var + 1e-5f);
  }
}

// ---------------- K2: normalize + pack xn (bf16) ----------------
// apack: [b(16)][mt(32)][ks(4)][k8(8)][m(128)][8], elem = xn[b][c=ks*64+k8*8+j][hw=mt*128+m]
__global__ __launch_bounds__(256) void k_xn_pack(const float* __restrict__ x,
    const float* __restrict__ stats, unsigned short* __restrict__ apack){
  size_t id = (size_t)blockIdx.x*256 + threadIdx.x;
  int m=(int)(id&127), k8=(int)(id>>7)&7, ks=(int)(id>>10)&3, mt=(int)(id>>12)&31, b=(int)(id>>17);
  int hw = mt*128+m, c0 = ks*64+k8*8;
  const float* xp = x + ((size_t)(b*256 + c0))*4096 + hw;
  const float* st = stats + (size_t)(b*256+c0)*2;
  uint4v o;
  #pragma unroll
  for (int j=0;j<8;j+=2){
    float v0 = (xp[(size_t)j*4096]     - st[j*2])   * st[j*2+1];
    float v1 = (xp[(size_t)(j+1)*4096] - st[j*2+2]) * st[j*2+3];
    o[j>>1] = pk2bf(v0, v1);
  }
  *(uint4v*)(apack + id*8) = o;
}

// ---------------- K3: fused (gate*value) GEMM + z GEMM with fused affine+dot -> sim ----------------
// Grid 16 x 5 x 32 (XCD-swizzled). Block p<4: channels [p*64,p*64+64) of BOTH gate and value
// for a 128-hw tile; epilogue writes product bf16 into gvpack (apack layout).
// Block p==4: z (128 ch); epilogue computes sim[pos] = sum_c (z*g0+b0)(z*g1+b1) / sqrt(128)
// (RoPE rotation cancels in same-position dot products).
__global__ __launch_bounds__(256,2) void k_gvzf(
    const unsigned short* __restrict__ Ap, const unsigned short* __restrict__ Wc,
    const float* __restrict__ biases, const float* __restrict__ gm, const float* __restrict__ bt,
    unsigned short* __restrict__ gvp, float* __restrict__ sim){
  __shared__ alignas(16) unsigned short lds[2][2][8192];   // [buf][W/X][16KB]
  __shared__ float red[2][4][16][2];
  int orig = blockIdx.x;
  int wg = (orig&7)*320 + (orig>>3);           // bijective XCD swizzle (2560%8==0)
  int b = wg/160; int r = wg - b*160; int p = r>>5; int mt = r&31;
  const unsigned short* Xt = Ap + (size_t)(b*32+mt)*32768;
  int t = threadIdx.x, lane = t&63;
  int wo = (t>>6)>>1, wm = (t>>6)&1;

  #define STAGEGV(buf, kss) do{ \
    _Pragma("unroll") \
    for (int i_=0;i_<4;i_++){ \
      int idx_ = i_*256 + t; \
      int k8_ = idx_>>7, slot_ = idx_&127; \
      int half_ = slot_>>6, sl_ = slot_&63; \
      int nt_, n_; \
      if (p<4){ nt_ = (p>>1) + half_*2; n_ = ((p&1)<<6) | sl_; } \
      else    { nt_ = 4; n_ = slot_; } \
      gload16(Wc + ((size_t)(nt_*4+(kss)))*8192 + (size_t)(k8_*128+n_)*8, &lds[buf][0][(size_t)idx_*8]); \
      gload16(Xt + (size_t)(kss)*8192 + (size_t)idx_*8, &lds[buf][1][(size_t)idx_*8]); \
    } \
  }while(0)

  f32x4 accg[2][4]={}, accv[2][4]={};

  #define CGV(buf) do{ \
    _Pragma("unroll") \
    for (int kf_=0;kf_<2;kf_++){ \
      int k8l_ = kf_*4 + (lane>>4); \
      short8 wg_[2], wv_[2], xf_[4]; \
      _Pragma("unroll") for (int ci_=0;ci_<2;ci_++){ \
        int sg_ = wo*32 + ci_*16 + (lane&15); \
        wg_[ci_] = *(const short8*)&lds[buf][0][(size_t)(k8l_*128 + sg_)*8]; \
        wv_[ci_] = *(const short8*)&lds[buf][0][(size_t)(k8l_*128 + 64 + sg_)*8]; } \
      _Pragma("unroll") for (int mj_=0;mj_<4;mj_++) \
        xf_[mj_] = *(const short8*)&lds[buf][1][(size_t)(k8l_*128 + wm*64 + mj_*16 + (lane&15))*8]; \
      _Pragma("unroll") for (int ci_=0;ci_<2;ci_++) \
        _Pragma("unroll") for (int mj_=0;mj_<4;mj_++){ \
          accg[ci_][mj_] = __builtin_amdgcn_mfma_f32_16x16x32_bf16(wg_[ci_], xf_[mj_], accg[ci_][mj_],0,0,0); \
          accv[ci_][mj_] = __builtin_amdgcn_mfma_f32_16x16x32_bf16(wv_[ci_], xf_[mj_], accv[ci_][mj_],0,0,0); } \
    } \
  }while(0)

  STAGEGV(0,0);
  __syncthreads();
  #pragma unroll
  for (int ks=0; ks<4; ++ks){
    int cur = ks&1;
    if (ks<3) STAGEGV(cur^1, ks+1);
    CGV(cur);
    __syncthreads();
  }

  if (p<4){
    #pragma unroll
    for (int ci=0;ci<2;ci++){
      int c = p*64 + wo*32 + ci*16 + ((lane>>4)<<2);
      f32x4 bg = *(const f32x4*)&biases[c];
      f32x4 bv = *(const f32x4*)&biases[256+c];
      int ksO = c>>6, k8O = (c>>3)&7, j0 = c&7;
      size_t base = ((size_t)(b*32+mt)*4 + ksO)*8192 + (size_t)(k8O*128)*8 + j0;
      #pragma unroll
      for (int mj=0;mj<4;mj++){
        int m = wm*64 + mj*16 + (lane&15);
        f32x4 pg = accg[ci][mj] + bg;
        f32x4 pv = accv[ci][mj] + bv;
        uint2v pk;
        pk[0] = pk2bf(pg[0]*pv[0], pg[1]*pv[1]);
        pk[1] = pk2bf(pg[2]*pv[2], pg[3]*pv[3]);
        *(uint2v*)(gvp + base + (size_t)m*8) = pk;
      }
    }
  } else {
    // fused affine + same-position q.k (RoPE cancels)
    float part[4] = {0.f,0.f,0.f,0.f};
    #pragma unroll
    for (int ci=0;ci<2;ci++){
      int cq = wo*32 + ci*16 + ((lane>>4)<<2);
      f32x4 bz0 = *(const f32x4*)&biases[512+cq];
      f32x4 bz1 = *(const f32x4*)&biases[512+64+cq];
      f32x4 g0a = *(const f32x4*)&gm[cq],      g1a = *(const f32x4*)&gm[128+cq];
      f32x4 b0a = *(const f32x4*)&bt[cq],      b1a = *(const f32x4*)&bt[128+cq];
      f32x4 g0b = *(const f32x4*)&gm[64+cq],   g1b = *(const f32x4*)&gm[192+cq];
      f32x4 b0b = *(const f32x4*)&bt[64+cq],   b1b = *(const f32x4*)&bt[192+cq];
      #pragma unroll
      for (int mj=0;mj<4;mj++){
        f32x4 z0 = accg[ci][mj] + bz0;
        f32x4 z1 = accv[ci][mj] + bz1;
        f32x4 c0 = (z0*g0a + b0a) * (z0*g1a + b1a);
        f32x4 c1 = (z1*g0b + b0b) * (z1*g1b + b1b);
        part[mj] += c0[0]+c0[1]+c0[2]+c0[3] + c1[0]+c1[1]+c1[2]+c1[3];
      }
    }
    #pragma unroll
    for (int mj=0;mj<4;mj++){
      float rr = part[mj];
      rr += __shfl_xor(rr, 16);
      rr += __shfl_xor(rr, 32);
      if (lane < 16) red[wm][mj][lane][wo] = rr;
    }
    __syncthreads();
    if (t < 128){
      int wmq = t>>6, mjq = (t>>4)&3, lq = t&15;
      float s = red[wmq][mjq][lq][0] + red[wmq][mjq][lq][1];
      sim[(size_t)b*4096 + mt*128 + wmq*64 + mjq*16 + lq] = s * 0.08838834764831845f;
    }
  }
  #undef STAGEGV
  #undef CGV
}

// ---------------- K4: proj GEMM with fused V = A*gv + xn staging ----------------
// Grid 16 x 32 (XCD-swizzled), 512 threads. Block (b,mt): all 256 outputs for a 128-hw tile.
// V computed once per tile in-register, ds_write to LDS; W streamed 32 KB chunks.
__global__ __launch_bounds__(512,1) void k_projf(
    const unsigned short* __restrict__ gvp, const unsigned short* __restrict__ Xp,
    const unsigned short* __restrict__ Wp, const float* __restrict__ biases,
    const float* __restrict__ A, float* __restrict__ out){
  extern __shared__ unsigned short sm[];
  unsigned short* Wl0 = sm;           // 32 KB
  unsigned short* Wl1 = sm + 16384;   // 32 KB
  unsigned short* Vl0 = sm + 32768;   // 16 KB
  unsigned short* Vl1 = sm + 40960;   // 16 KB
  int orig = blockIdx.x;
  int wg = (orig&7)*64 + (orig>>3);   // bijective (512%8==0)
  int b = wg>>5, mt = wg&31;
  int t = threadIdx.x, lane = t&63, wid = t>>6;
  int wo = wid>>1, wm = wid&1;
  size_t tbase = (size_t)(b*32+mt)*32768;
  float a = A[(size_t)b*4096 + mt*128 + (t&127)];
  uint4v Gr[2], Xr[2];

  #define LOADV(kss) do{ _Pragma("unroll") for (int i_=0;i_<2;i_++){ \
      Gr[i_] = *(const uint4v*)(gvp + tbase + (size_t)(kss)*8192 + (size_t)(i_*512+t)*8); \
      Xr[i_] = *(const uint4v*)(Xp  + tbase + (size_t)(kss)*8192 + (size_t)(i_*512+t)*8); } }while(0)

  #define WRITEV(DST) do{ _Pragma("unroll") for (int i_=0;i_<2;i_++){ \
      uint4v g_=Gr[i_], x_=Xr[i_]; uint4v o_; \
      _Pragma("unroll") for (int w_=0;w_<4;w_++){ \
        float gA_=bf2f((unsigned short)(g_[w_]&0xffff)), gB_=bf2f((unsigned short)(g_[w_]>>16)); \
        float xA_=bf2f((unsigned short)(x_[w_]&0xffff)), xB_=bf2f((unsigned short)(x_[w_]>>16)); \
        o_[w_] = pk2bf(a*gA_+xA_, a*gB_+xB_); } \
      *(uint4v*)&(DST)[(size_t)(i_*512+t)*8] = o_; } }while(0)

  #define STAGEW(DST, kss) do{ _Pragma("unroll") for (int i_=0;i_<4;i_++){ \
      int idx_ = i_*512+t; \
      int k8_ = idx_>>8, rest_ = idx_&255, oh_ = rest_>>7, o_ = rest_&127; \
      gload16(Wp + (((size_t)(oh_*4+(kss))*8 + k8_)*128 + o_)*8, &(DST)[(size_t)idx_*8]); } }while(0)

  f32x4 acc[4][4]={};

  #define CPJ(WBUF, VBUF) do{ \
    _Pragma("unroll") for (int kf_=0;kf_<2;kf_++){ \
      int k8l_ = kf_*4 + (lane>>4); \
      short8 wf_[4], vf_[4]; \
      _Pragma("unroll") for (int ci_=0;ci_<4;ci_++) \
        wf_[ci_] = *(const short8*)&(WBUF)[(size_t)(k8l_*256 + wo*64 + ci_*16 + (lane&15))*8]; \
      _Pragma("unroll") for (int mj_=0;mj_<4;mj_++) \
        vf_[mj_] = *(const short8*)&(VBUF)[(size_t)(k8l_*128 + wm*64 + mj_*16 + (lane&15))*8]; \
      _Pragma("unroll") for (int ci_=0;ci_<4;ci_++) \
        _Pragma("unroll") for (int mj_=0;mj_<4;mj_++) \
          acc[ci_][mj_] = __builtin_amdgcn_mfma_f32_16x16x32_bf16(wf_[ci_], vf_[mj_], acc[ci_][mj_],0,0,0); \
    } }while(0)

  LOADV(0); STAGEW(Wl0, 0); WRITEV(Vl0);
  __syncthreads();
  // ks=0
  LOADV(1); STAGEW(Wl1, 1);
  CPJ(Wl0, Vl0);
  WRITEV(Vl1);
  __syncthreads();
  // ks=1
  LOADV(2); STAGEW(Wl0, 2);
  CPJ(Wl1, Vl1);
  WRITEV(Vl0);
  __syncthreads();
  // ks=2
  LOADV(3); STAGEW(Wl1, 3);
  CPJ(Wl0, Vl0);
  WRITEV(Vl1);
  __syncthreads();
  // ks=3
  CPJ(Wl1, Vl1);
  __syncthreads();

  // epilogue: two passes of LDS transpose (rows=o, cols=hw) -> coalesced out rows
  float* fl = (float*)sm;   // 64 KB
  #pragma unroll
  for (int pp=0; pp<2; ++pp){
    if ((wo>>1) == pp){
      #pragma unroll
      for (int ci=0;ci<4;ci++){
        int oq = (wo&1)*64 + ci*16 + ((lane>>4)<<2);
        #pragma unroll
        for (int mj=0;mj<4;mj++){
          int m = wm*64 + mj*16 + (lane&15);
          *(f32x4*)&fl[(size_t)m*128 + (oq ^ (((m>>2)&31)<<2))] = acc[ci][mj];
        }
      }
    }
    __syncthreads();
    #pragma unroll
    for (int it=0; it<8; it++){
      int gid = it*512 + t;
      int o_r = gid>>5, hq = (gid&31)<<2;
      int s = ((hq>>2)&31)<<2;
      float bo = biases[640 + pp*128 + o_r];
      f32x4 vo;
      #pragma unroll
      for (int k=0;k<4;k++) vo[k] = fl[(size_t)(hq+k)*128 + (o_r ^ s)] + bo;
      *(f32x4*)&out[((size_t)(b*256 + pp*128 + o_r))*4096 + mt*128 + hq] = vo;
    }
    __syncthreads();
  }
  #undef LOADV
  #undef WRITEV
  #undef STAGEW
  #undef CPJ
}

// ---------------- K5: per-batch softmax over 4096 -> A ----------------
__global__ __launch_bounds__(256) void k_softmax(const float* __restrict__ sim, float* __restrict__ A){
  int b = blockIdx.x, t = threadIdx.x, lane = t&63, wid = t>>6;
  const f32x4* s4 = (const f32x4*)(sim + (size_t)b*4096);
  f32x4 v[4];
  float mx = -3.4e38f;
  #pragma unroll
  for (int i=0;i<4;i++){
    v[i] = s4[i*256+t];
    #pragma unroll
    for (int w=0;w<4;w++) mx = fmaxf(mx, v[i][w]);
  }
  #pragma unroll
  for (int off=32; off; off>>=1) mx = fmaxf(mx, __shfl_xor(mx, off));
  __shared__ float sr1[4], sr2[4];
  if (lane==0) sr1[wid]=mx;
  __syncthreads();
  mx = fmaxf(fmaxf(sr1[0],sr1[1]), fmaxf(sr1[2],sr1[3]));
  float sum=0.f;
  #pragma unroll
  for (int i=0;i<4;i++)
    #pragma unroll
    for (int w=0;w<4;w++){ float e = expf(v[i][w]-mx); v[i][w]=e; sum+=e; }
  #pragma unroll
  for (int off=32; off; off>>=1) sum += __shfl_xor(sum, off);
  if (lane==0) sr2[wid]=sum;
  __syncthreads();
  sum = sr2[0]+sr2[1]+sr2[2]+sr2[3];
  float invs = 1.0f/sum;
  f32x4* Ab = (f32x4*)(A + (size_t)b*4096);
  #pragma unroll
  for (int i=0;i<4;i++){
    f32x4 a;
    #pragma unroll
    for (int w=0;w<4;w++) a[w] = v[i][w]*invs;
    Ab[i*256+t] = a;
  }
}

// ---------------- launch ----------------
extern "C" void kernel_launch(void* const* d_in, const int* in_sizes, int n_in,
                              void* d_out, int out_size, void* d_ws, size_t ws_size,
                              hipStream_t stream){
  const float* x  = (const float*)d_in[0];
  const float* gW = (const float*)d_in[1];
  const float* gB = (const float*)d_in[2];
  const float* vW = (const float*)d_in[3];
  const float* vB = (const float*)d_in[4];
  const float* zW = (const float*)d_in[5];
  const float* zB = (const float*)d_in[6];
  const float* gm = (const float*)d_in[7];
  const float* bt = (const float*)d_in[8];
  const float* pW = (const float*)d_in[9];
  const float* pB = (const float*)d_in[10];

  char* ws = (char*)d_ws;
  float* stats           = (float*)(ws + 0);                  //  32 KB
  float* biases          = (float*)(ws + 32768);              //  3.5 KB
  float* sim             = (float*)(ws + 40960);              // 256 KB
  unsigned short* wcat   = (unsigned short*)(ws + 303104);    // 320 KB bf16
  unsigned short* proj   = (unsigned short*)(ws + 958464);    // 128 KB bf16
  unsigned short* apack  = (unsigned short*)(ws + 2097152);   // 33.5 MB bf16 (xn)
  unsigned short* gvpack = (unsigned short*)(ws + 35651584);  // 33.5 MB bf16 -> total 69,206,016 B

  float* out = (float*)d_out;
  float* A   = out + 16777216;  // final A slot (16x64x64 fp32)

  hipLaunchKernelGGL(k_pack_w,  dim3(112),  dim3(256), 0, stream, gW, vW, zW, pW, gB, vB, zB, pB, wcat, proj, biases);
  hipLaunchKernelGGL(k_stats,   dim3(4096), dim3(256), 0, stream, x, stats);
  hipLaunchKernelGGL(k_xn_pack, dim3(8192), dim3(256), 0, stream, x, stats, apack);
  hipLaunchKernelGGL(k_gvzf,    dim3(2560), dim3(256), 0, stream, apack, wcat, biases, gm, bt, gvpack, sim);
  hipLaunchKernelGGL(k_softmax, dim3(16),   dim3(256), 0, stream, sim, A);
  hipLaunchKernelGGL(k_projf,   dim3(512),  dim3(512), 98304, stream, gvpack, apack, proj, biases, A, out);
  (void)in_sizes; (void)n_in; (void)out_size; (void)ws_size;
}